// Round 10
// baseline (644.453 us; speedup 1.0000x reference)
//
#include <hip/hip_runtime.h>
#include <hip/hip_bf16.h>

#define D_MODEL 512
#define NHEAD 8
#define NSEQ 512
#define BATCH 16
#define LWIN 64
#define S2C 0.18033688f   // 0.125 * log2(e)
#define L2E 1.44269504f

typedef short s16x8 __attribute__((ext_vector_type(8)));
typedef float f32x4 __attribute__((ext_vector_type(4)));

__device__ inline unsigned short f2bf(float f) {
    unsigned int u = __float_as_uint(f);
    u = (u + 0x7fffu + ((u >> 16) & 1u)) >> 16;   // RNE
    return (unsigned short)u;
}
__device__ inline float4 bfl4(const unsigned short* p) {   // 4 bf16 -> float4
    uint2 u = *(const uint2*)p;
    return make_float4(__uint_as_float(u.x << 16), __uint_as_float(u.x & 0xffff0000u),
                       __uint_as_float(u.y << 16), __uint_as_float(u.y & 0xffff0000u));
}
__device__ inline int sw4(int r) { return (r + (r >> 2)) & 3; }

#define GLD16(g, l) __builtin_amdgcn_global_load_lds( \
    (const __attribute__((address_space(1))) void*)(g), \
    (__attribute__((address_space(3))) void*)(l), 16, 0, 0)

struct WP { const float* p[10]; };

// ---------------------------------------------------------------------------
// front: wconv (blocks 0..4607) + zfill Slocal_b (4608..6655) + embed (6656..)
// ---------------------------------------------------------------------------
__global__ __launch_bounds__(256) void front_kernel(
    WP wp, unsigned short* __restrict__ Wb, unsigned short* __restrict__ Z,
    const int* __restrict__ q, const int* __restrict__ r, const int* __restrict__ qry,
    const float* __restrict__ M_emb, const float* __restrict__ E_emb,
    const float* __restrict__ P,
    unsigned short* __restrict__ Mb, unsigned short* __restrict__ Eb)
{
    const int blk = blockIdx.x, tid = threadIdx.x;
    if (blk < 4608) {
        const long e = ((long)blk * 256 + tid) * 4;
        const float* src; long loc;
        if (e < 3145728) { int rg = (int)(e / 786432); src = wp.p[rg]; loc = e - (long)rg * 786432; }
        else { long j = e - 3145728; int rg = (int)(j >> 18); src = wp.p[4 + rg]; loc = j - ((long)rg << 18); }
        float4 v = *(const float4*)(src + loc);
        ushort4 o; o.x = f2bf(v.x); o.y = f2bf(v.y); o.z = f2bf(v.z); o.w = f2bf(v.w);
        *(ushort4*)(Wb + e) = o;
    } else if (blk < 6656) {
        const long i = ((long)(blk - 4608) * 256 + tid) * 8;
        *(uint4*)(Z + i) = make_uint4(0u, 0u, 0u, 0u);
    } else {
        const int t = (blk - 6656) * 2 + (tid >> 7);    // row b*N+n
        const int i = tid & 127;
        const int n = t & (NSEQ - 1);
        const int x = q[t] + 10000 * r[t];
        const int e = qry[t];
        float4 a = ((const float4*)(M_emb + (long)x * D_MODEL))[i];
        float4 p4 = ((const float4*)(P + (long)n * D_MODEL))[i];
        float4 ev = ((const float4*)(E_emb + (long)e * D_MODEL))[i];
        float4 mv = make_float4(a.x + p4.x, a.y + p4.y, a.z + p4.z, a.w + p4.w);
        ushort4 mb; mb.x = f2bf(mv.x); mb.y = f2bf(mv.y); mb.z = f2bf(mv.z); mb.w = f2bf(mv.w);
        ushort4 eb; eb.x = f2bf(ev.x); eb.y = f2bf(ev.y); eb.z = f2bf(ev.z); eb.w = f2bf(ev.w);
        *(ushort4*)(Mb + (long)t * D_MODEL + i * 4) = mb;
        *(ushort4*)(Eb + (long)t * D_MODEL + i * 4) = eb;
    }
}

// ---------------------------------------------------------------------------
// bf16 MFMA GEMM body, 128M x 64N tile, GLD16 staging (round-8 core).
// All residuals and outputs bf16; fp32 accumulate in-register/epilogue.
//  - Cb (+crem row remap), Cb2 second compact bf16 output (Tloc)
//  - r1/r2 full residuals, tl sparse residual (rows n>=448)
// ---------------------------------------------------------------------------
struct GArgs {
    const unsigned short* A; const unsigned short* A2; int nsplit;
    const unsigned short* W; const float* bias;
    unsigned short* Cb; int ldcb; int crem;
    unsigned short* Cb2; int ldcb2;
    const unsigned short* r1; const unsigned short* r2; const unsigned short* tl;
    int relu; int arem;
};

__device__ __forceinline__ void gemm_body(unsigned short* Sh, const GArgs& G,
                                          int n0, int m0, int tid)
{
    unsigned short* As = Sh;
    unsigned short* Ws = Sh + 4096;
    float* Shf = (float*)Sh;

    const int lane = tid & 63, wid = tid >> 6;
    const int lm = lane & 15;
    const int lq = lane >> 4;
    const unsigned short* Asel = (n0 >= G.nsplit) ? G.A2 : G.A;

    const int rlane = lane >> 2, clane = lane & 3;
    const int lr0 = wid * 16 + rlane;          // 0..63
    const int lr1 = 64 + lr0;                  // 64..127 (A only)
    int rgA0 = m0 + lr0, rgA1 = m0 + lr1;
    if (G.arem) {
        rgA0 = ((rgA0 >> 6) << 9) + (NSEQ - LWIN) + (rgA0 & 63);
        rgA1 = ((rgA1 >> 6) << 9) + (NSEQ - LWIN) + (rgA1 & 63);
    }
    const unsigned short* pA0 = Asel + (long)rgA0 * 512 + ((clane ^ sw4(lr0)) << 3);
    const unsigned short* pA1 = Asel + (long)rgA1 * 512 + ((clane ^ sw4(lr1)) << 3);
    const unsigned short* pW0 = G.W + (long)(n0 + lr0) * 512 + ((clane ^ sw4(lr0)) << 3);
    unsigned short* lA0 = As + (wid * 16) * 32;
    unsigned short* lA1 = As + (64 + wid * 16) * 32;
    unsigned short* lW0 = Ws + (wid * 16) * 32;

    f32x4 acc[2][4];
    #pragma unroll
    for (int i = 0; i < 2; ++i)
        #pragma unroll
        for (int j = 0; j < 4; ++j) acc[i][j] = (f32x4){0.f, 0.f, 0.f, 0.f};

    for (int k0 = 0; k0 < 512; k0 += 32) {
        __syncthreads();
        GLD16(pA0 + k0, lA0);
        GLD16(pA1 + k0, lA1);
        GLD16(pW0 + k0, lW0);
        __syncthreads();

        s16x8 af[2], wf[4];
        #pragma unroll
        for (int i = 0; i < 2; ++i) {
            const int ra = wid * 32 + i * 16 + lm;
            af[i] = *(const s16x8*)&As[ra * 32 + ((lq ^ sw4(ra)) << 3)];
        }
        #pragma unroll
        for (int j = 0; j < 4; ++j) {
            const int rw = j * 16 + lm;
            wf[j] = *(const s16x8*)&Ws[rw * 32 + ((lq ^ sw4(rw)) << 3)];
        }
        #pragma unroll
        for (int i = 0; i < 2; ++i)
            #pragma unroll
            for (int j = 0; j < 4; ++j)
                acc[i][j] = __builtin_amdgcn_mfma_f32_16x16x32_bf16(af[i], wf[j], acc[i][j], 0, 0, 0);
    }

    const int fr = lane & 15;
    const int q4 = (lane >> 4) * 4;
    for (int qtr = 0; qtr < 4; ++qtr) {
        __syncthreads();
        if (wid == qtr) {
            #pragma unroll
            for (int j = 0; j < 4; ++j) {
                const int lcol = j * 16 + fr;
                const float bv = G.bias[n0 + lcol];
                #pragma unroll
                for (int i = 0; i < 2; ++i) {
                    #pragma unroll
                    for (int rg = 0; rg < 4; ++rg) {
                        float v = acc[i][j][rg] + bv;
                        if (G.relu) v = fmaxf(v, 0.f);
                        Shf[(i * 16 + q4 + rg) * 68 + lcol] = v;
                    }
                }
            }
        }
        __syncthreads();
        #pragma unroll
        for (int it = 0; it < 2; ++it) {
            const int flat = it * 256 + tid;
            const int rowq = flat >> 4, k4 = flat & 15;
            const int grow = m0 + qtr * 32 + rowq;
            const int gcol = n0 + k4 * 4;
            float4 f = *(const float4*)&Shf[rowq * 68 + k4 * 4];
            if (G.r1) {
                float4 a = bfl4(G.r1 + (long)grow * 512 + gcol);
                f.x += a.x; f.y += a.y; f.z += a.z; f.w += a.w;
            }
            if (G.r2) {
                float4 b = bfl4(G.r2 + (long)grow * 512 + gcol);
                f.x += b.x; f.y += b.y; f.z += b.z; f.w += b.w;
            }
            if (G.tl) {
                const int n = grow & 511;
                if (n >= NSEQ - LWIN) {
                    float4 c = bfl4(G.tl + ((long)(grow >> 9) * 64 + (n - (NSEQ - LWIN))) * 512 + gcol);
                    f.x += c.x; f.y += c.y; f.z += c.z; f.w += c.w;
                }
            }
            ushort4 u; u.x = f2bf(f.x); u.y = f2bf(f.y); u.z = f2bf(f.z); u.w = f2bf(f.w);
            if (G.Cb) {
                const int crow = G.crem ? (((grow >> 6) << 9) + (NSEQ - LWIN) + (grow & 63)) : grow;
                *(ushort4*)(G.Cb + (long)crow * G.ldcb + gcol) = u;
            }
            if (G.Cb2) *(ushort4*)(G.Cb2 + (long)grow * G.ldcb2 + gcol) = u;
        }
    }
}

__global__ __launch_bounds__(256) void gemm_bf16(GArgs g0, GArgs g1, int msplit)
{
    __shared__ __align__(16) unsigned short Sh[6144];
    int m0 = blockIdx.y * 128;
    const GArgs& G = (m0 < msplit) ? g0 : g1;
    if (m0 >= msplit) m0 -= msplit;
    gemm_body(Sh, G, blockIdx.x * 64, m0, threadIdx.x);
}

// ---------------------------------------------------------------------------
// attn_w body (transposed MFMA): head-mean base probs via saved (m,l).
// ---------------------------------------------------------------------------
__device__ __forceinline__ void attnw_body(unsigned short* Ks,
    const unsigned short* __restrict__ Q, const unsigned short* __restrict__ K,
    const float* __restrict__ stats, float* __restrict__ AW, int ldq, int ldk,
    int kt, int qt, int b, int tid)
{
    if (kt > qt) {
        const int tx = tid & 15, ty = tid >> 4;
        #pragma unroll
        for (int i = 0; i < 4; ++i)
            *(float4*)(AW + ((long)b * NSEQ + qt * 64 + ty * 4 + i) * NSEQ + kt * 64 + tx * 4)
                = make_float4(0.f, 0.f, 0.f, 0.f);
        return;
    }
    const int lane = tid & 63, w = tid >> 6;
    const int lm = lane & 15, lq = lane >> 4;
    const int skey = tid >> 3, sd = (tid & 7) * 8;
    const long qrow = (long)b * NSEQ + qt * 64 + w * 16 + lm;

    f32x4 aw[4];
    #pragma unroll
    for (int t = 0; t < 4; ++t) aw[t] = (f32x4){0.f,0.f,0.f,0.f};

    for (int h = 0; h < NHEAD; ++h) {
        __syncthreads();
        {
            const long kb = ((long)b * NSEQ + kt * 64) * ldk + h * 64;
            *(s16x8*)&Ks[skey * 72 + sd] = *(const s16x8*)(K + kb + (long)skey * ldk + sd);
            *(s16x8*)&Ks[(skey + 32) * 72 + sd] = *(const s16x8*)(K + kb + (long)(skey + 32) * ldk + sd);
        }
        __syncthreads();
        s16x8 a0, a1;
        {
            const unsigned short* qp = Q + qrow * ldq + h * 64 + lq * 8;
            a0 = *(const s16x8*)qp; a1 = *(const s16x8*)(qp + 32);
        }
        f32x4 sc[4];
        #pragma unroll
        for (int t = 0; t < 4; ++t) sc[t] = (f32x4){0.f,0.f,0.f,0.f};
        #pragma unroll
        for (int t = 0; t < 4; ++t) {
            s16x8 k0 = *(const s16x8*)&Ks[(t * 16 + lm) * 72 + lq * 8];
            s16x8 k1 = *(const s16x8*)&Ks[(t * 16 + lm) * 72 + lq * 8 + 32];
            sc[t] = __builtin_amdgcn_mfma_f32_16x16x32_bf16(k0, a0, sc[t], 0, 0, 0);
            sc[t] = __builtin_amdgcn_mfma_f32_16x16x32_bf16(k1, a1, sc[t], 0, 0, 0);
        }
        float2 ml = *(const float2*)(stats + (((long)b * NHEAD + h) * NSEQ + qt * 64 + w * 16 + lm) * 2);
        const float mb2 = ml.x * L2E;
        const float sca = 0.125f / ml.y;
        #pragma unroll
        for (int t = 0; t < 4; ++t)
            #pragma unroll
            for (int r = 0; r < 4; ++r) {
                const bool masked = (kt == qt) && (t * 16 + lq * 4 + r > w * 16 + lm);
                if (!masked) aw[t][r] += exp2f(sc[t][r] * S2C - mb2) * sca;
            }
    }
    #pragma unroll
    for (int t = 0; t < 4; ++t)
        *(float4*)(AW + qrow * NSEQ + kt * 64 + t * 16 + lq * 4) = float4{aw[t][0], aw[t][1], aw[t][2], aw[t][3]};
}

// merged: glob+local QKV GEMM (blocks 0..1727) + attn_w (1728..2751)
__global__ __launch_bounds__(256) void gemm_attnw(GArgs g0, GArgs g1, int msplit,
    const unsigned short* Q, const unsigned short* K, const float* stats,
    float* AW, int ldq, int ldk)
{
    __shared__ __align__(16) unsigned short Sh[6144];
    const int x = blockIdx.x;
    if (x < 1728) {
        int m0 = (x / 24) * 128;
        const GArgs& G = (m0 < msplit) ? g0 : g1;
        if (m0 >= msplit) m0 -= msplit;
        gemm_body(Sh, G, (x % 24) * 64, m0, threadIdx.x);
    } else {
        const int id = x - 1728;
        attnw_body(Sh, Q, K, stats, AW, ldq, ldk, id & 7, (id >> 3) & 7, id >> 6, threadIdx.x);
    }
}

// ---------------------------------------------------------------------------
// Transposed MFMA flash attention, paired q-tiles (round-8 core, dual args).
// ---------------------------------------------------------------------------
struct FArgs {
    const unsigned short* Q; const unsigned short* K; const unsigned short* V;
    unsigned short* O; float* stats; int Nq, Nkv, ldq, ldkv, causal;
};

__global__ __launch_bounds__(256) void flash_mfma(FArgs f0, FArgs f1, int xsplit)
{
    __shared__ __align__(16) unsigned short Ks[64 * 72];   // [key][dim]
    __shared__ __align__(16) unsigned short Pl[64 * 72];   // [q][key] bf16
    __shared__ __align__(16) unsigned int   Vt[64 * 36];   // [dim][keypair] swizzled

    const FArgs& F = ((int)blockIdx.x < xsplit) ? f0 : f1;
    const int bx = ((int)blockIdx.x < xsplit) ? blockIdx.x : (blockIdx.x - xsplit);

    const int tid = threadIdx.x, lane = tid & 63, w = tid >> 6;
    const int lm = lane & 15, lq = lane >> 4;
    const int h = blockIdx.y, b = blockIdx.z;
    const int Nq = F.Nq, Nkv = F.Nkv, ldq = F.ldq, ldkv = F.ldkv, causal = F.causal;
    const int nqt = Nq >> 6;
    const int qa = bx, qb = nqt - 1 - qa;
    const bool single = (qa == qb);

    s16x8 aqA0, aqA1, aqB0, aqB1;
    {
        const unsigned short* qp = F.Q + ((long)b * Nq + qb * 64 + w * 16 + lm) * ldq + h * 64 + lq * 8;
        aqB0 = *(const s16x8*)qp; aqB1 = *(const s16x8*)(qp + 32);
    }
    if (!single) {
        const unsigned short* qp = F.Q + ((long)b * Nq + qa * 64 + w * 16 + lm) * ldq + h * 64 + lq * 8;
        aqA0 = *(const s16x8*)qp; aqA1 = *(const s16x8*)(qp + 32);
    }

    float mA = -INFINITY, lA = 0.f, mB = -INFINITY, lB = 0.f;
    f32x4 oA[4], oB[4];
    #pragma unroll
    for (int t = 0; t < 4; ++t) { oA[t] = (f32x4){0.f,0.f,0.f,0.f}; oB[t] = (f32x4){0.f,0.f,0.f,0.f}; }

    const int nkt = causal ? (qb + 1) : (Nkv >> 6);
    const int skey = tid >> 3, sd = (tid & 7) * 8;

    s16x8 kr0, kr1; uint4 vr0, vr1;
    {
        const long kb = ((long)b * Nkv) * ldkv + h * 64;
        kr0 = *(const s16x8*)(F.K + kb + (long)skey * ldkv + sd);
        kr1 = *(const s16x8*)(F.K + kb + (long)(skey + 32) * ldkv + sd);
        const unsigned short* vp = F.V + ((long)b * Nkv + 2 * skey) * ldkv + h * 64 + sd;
        vr0 = *(const uint4*)vp; vr1 = *(const uint4*)(vp + ldkv);
    }

    auto process = [&](s16x8 a0, s16x8 a1, float& m, float& l, f32x4* oacc, bool diag) {
        f32x4 sc[4];
        #pragma unroll
        for (int t = 0; t < 4; ++t) sc[t] = (f32x4){0.f,0.f,0.f,0.f};
        #pragma unroll
        for (int t = 0; t < 4; ++t) {
            s16x8 k0 = *(const s16x8*)&Ks[(t * 16 + lm) * 72 + lq * 8];
            s16x8 k1 = *(const s16x8*)&Ks[(t * 16 + lm) * 72 + lq * 8 + 32];
            sc[t] = __builtin_amdgcn_mfma_f32_16x16x32_bf16(k0, a0, sc[t], 0, 0, 0);
            sc[t] = __builtin_amdgcn_mfma_f32_16x16x32_bf16(k1, a1, sc[t], 0, 0, 0);
        }
        if (diag) {
            #pragma unroll
            for (int t = 0; t < 4; ++t)
                #pragma unroll
                for (int r = 0; r < 4; ++r)
                    if (t * 16 + lq * 4 + r > w * 16 + lm) sc[t][r] = -INFINITY;
        }
        float mt = sc[0][0];
        #pragma unroll
        for (int t = 0; t < 4; ++t)
            #pragma unroll
            for (int r = 0; r < 4; ++r) mt = fmaxf(mt, sc[t][r]);
        mt = fmaxf(mt, __shfl_xor(mt, 16));
        mt = fmaxf(mt, __shfl_xor(mt, 32));
        const float mn = fmaxf(m, mt);
        const float al = exp2f((m - mn) * S2C);
        float rs = 0.f;
        #pragma unroll
        for (int t = 0; t < 4; ++t)
            #pragma unroll
            for (int r = 0; r < 4; ++r) {
                float p = exp2f((sc[t][r] - mn) * S2C);
                sc[t][r] = p; rs += p;
            }
        rs += __shfl_xor(rs, 16);
        rs += __shfl_xor(rs, 32);
        m = mn; l = l * al + rs;
        #pragma unroll
        for (int t = 0; t < 4; ++t) oacc[t] *= al;
        #pragma unroll
        for (int t = 0; t < 4; ++t) {
            ushort4 u;
            u.x = f2bf(sc[t][0]); u.y = f2bf(sc[t][1]);
            u.z = f2bf(sc[t][2]); u.w = f2bf(sc[t][3]);
            *(ushort4*)&Pl[(w * 16 + lm) * 72 + t * 16 + lq * 4] = u;
        }
        #pragma unroll
        for (int ks = 0; ks < 2; ++ks) {
            s16x8 bp = *(const s16x8*)&Pl[(w * 16 + lm) * 72 + ks * 32 + lq * 8];
            #pragma unroll
            for (int t = 0; t < 4; ++t) {
                const int row = t * 16 + lm;
                const int pg = ((lq >> 1) + 2 * ks) ^ ((row >> 3) & 3);
                s16x8 av = *(const s16x8*)((const unsigned short*)Vt + row * 72 + pg * 16 + (lq & 1) * 8);
                oacc[t] = __builtin_amdgcn_mfma_f32_16x16x32_bf16(av, bp, oacc[t], 0, 0, 0);
            }
        }
    };

    for (int kt = 0; kt < nkt; ++kt) {
        __syncthreads();
        *(s16x8*)&Ks[skey * 72 + sd] = kr0;
        *(s16x8*)&Ks[(skey + 32) * 72 + sd] = kr1;
        {
            unsigned pw[8];
            pw[0] = (vr0.x & 0xffffu) | (vr1.x << 16);
            pw[1] = (vr0.x >> 16)     | (vr1.x & 0xffff0000u);
            pw[2] = (vr0.y & 0xffffu) | (vr1.y << 16);
            pw[3] = (vr0.y >> 16)     | (vr1.y & 0xffff0000u);
            pw[4] = (vr0.z & 0xffffu) | (vr1.z << 16);
            pw[5] = (vr0.z >> 16)     | (vr1.z & 0xffff0000u);
            pw[6] = (vr0.w & 0xffffu) | (vr1.w << 16);
            pw[7] = (vr0.w >> 16)     | (vr1.w & 0xffff0000u);
            #pragma unroll
            for (int j = 0; j < 8; ++j) {
                const int row = sd + j;
                const int col = (((skey >> 3) ^ ((row >> 3) & 3)) << 3) | (skey & 7);
                Vt[row * 36 + col] = pw[j];
            }
        }
        __syncthreads();
        if (kt + 1 < nkt) {
            const long kb = ((long)b * Nkv + (kt + 1) * 64) * ldkv + h * 64;
            kr0 = *(const s16x8*)(F.K + kb + (long)skey * ldkv + sd);
            kr1 = *(const s16x8*)(F.K + kb + (long)(skey + 32) * ldkv + sd);
            const unsigned short* vp = F.V + ((long)b * Nkv + (kt + 1) * 64 + 2 * skey) * ldkv + h * 64 + sd;
            vr0 = *(const uint4*)vp; vr1 = *(const uint4*)(vp + ldkv);
        }
        process(aqB0, aqB1, mB, lB, oB, causal && (kt == qb));
        if (!single && (!causal || kt <= qa))
            process(aqA0, aqA1, mA, lA, oA, causal && (kt == qa));
    }

    {
        const float inv = 1.0f / lB;
        const long orow = ((long)b * Nq + qb * 64 + w * 16 + lm) * D_MODEL + h * 64;
        #pragma unroll
        for (int t = 0; t < 4; ++t) {
            ushort4 u;
            u.x = f2bf(oB[t][0] * inv); u.y = f2bf(oB[t][1] * inv);
            u.z = f2bf(oB[t][2] * inv); u.w = f2bf(oB[t][3] * inv);
            *(ushort4*)(F.O + orow + t * 16 + lq * 4) = u;
        }
    }
    if (!single) {
        const float inv = 1.0f / lA;
        const long orow = ((long)b * Nq + qa * 64 + w * 16 + lm) * D_MODEL + h * 64;
        #pragma unroll
        for (int t = 0; t < 4; ++t) {
            ushort4 u;
            u.x = f2bf(oA[t][0] * inv); u.y = f2bf(oA[t][1] * inv);
            u.z = f2bf(oA[t][2] * inv); u.w = f2bf(oA[t][3] * inv);
            *(ushort4*)(F.O + orow + t * 16 + lq * 4) = u;
        }
    }
    if (F.stats && lq == 0) {
        long idx = (((long)b * NHEAD + h) * Nq + qb * 64 + w * 16 + lm) * 2;
        F.stats[idx] = mB * 0.125f; F.stats[idx + 1] = lB;
        if (!single) {
            idx = (((long)b * NHEAD + h) * Nq + qa * 64 + w * 16 + lm) * 2;
            F.stats[idx] = mA * 0.125f; F.stats[idx + 1] = lA;
        }
    }
}

// ---------------------------------------------------------------------------
// LayerNorm, bf16 input (residuals pre-added upstream); optional fused pred.
// ---------------------------------------------------------------------------
__global__ __launch_bounds__(256) void ln_kernel(
    const unsigned short* __restrict__ X, const float* __restrict__ g,
    const float* __restrict__ bb, unsigned short* __restrict__ outb,
    const float* __restrict__ pw, const float* __restrict__ pb,
    float* __restrict__ outp)
{
    const long row = blockIdx.x;
    const int tid = threadIdx.x;
    __shared__ float red[256];
    const long base = row * D_MODEL;
    const unsigned ux = *(const unsigned*)(X + base + tid * 2);
    const float v0 = __uint_as_float(ux << 16);
    const float v1 = __uint_as_float(ux & 0xffff0000u);
    red[tid] = v0 + v1; __syncthreads();
    for (int s = 128; s > 0; s >>= 1) {
        if (tid < s) red[tid] += red[tid + s];
        __syncthreads();
    }
    const float mean = red[0] * (1.f / 512.f);
    __syncthreads();
    const float d0 = v0 - mean, d1 = v1 - mean;
    red[tid] = d0 * d0 + d1 * d1; __syncthreads();
    for (int s = 128; s > 0; s >>= 1) {
        if (tid < s) red[tid] += red[tid + s];
        __syncthreads();
    }
    const float rstd = rsqrtf(red[0] * (1.f / 512.f) + 1e-5f);
    const float2 gv = *(const float2*)(g + tid * 2);
    const float2 bv = *(const float2*)(bb + tid * 2);
    const float y0 = d0 * rstd * gv.x + bv.x;
    const float y1 = d1 * rstd * gv.y + bv.y;
    if (pw) {
        const float2 pv = *(const float2*)(pw + tid * 2);
        float s = y0 * pv.x + y1 * pv.y;
        __syncthreads();
        red[tid] = s; __syncthreads();
        for (int st = 128; st > 0; st >>= 1) {
            if (tid < st) red[tid] += red[tid + st];
            __syncthreads();
        }
        if (tid == 0) outp[row] = 1.f / (1.f + __expf(-(red[0] + pb[0])));
        return;
    }
    const unsigned o = (unsigned)f2bf(y0) | ((unsigned)f2bf(y1) << 16);
    *(unsigned*)(outb + base + tid * 2) = o;
}

// ---------------------------------------------------------------------------
extern "C" void kernel_launch(void* const* d_in, const int* in_sizes, int n_in,
                              void* d_out, int out_size, void* d_ws, size_t ws_size,
                              hipStream_t stream)
{
    const int*   q          = (const int*)d_in[0];
    const int*   r          = (const int*)d_in[1];
    const int*   qry        = (const int*)d_in[2];
    const float* M_emb      = (const float*)d_in[3];
    const float* E_emb      = (const float*)d_in[4];
    const float* P          = (const float*)d_in[5];
    const float* base_in_w  = (const float*)d_in[6];
    const float* base_in_b  = (const float*)d_in[7];
    const float* base_out_w = (const float*)d_in[8];
    const float* base_out_b = (const float*)d_in[9];
    const float* local_in_w = (const float*)d_in[10];
    const float* local_in_b = (const float*)d_in[11];
    const float* local_out_w= (const float*)d_in[12];
    const float* local_out_b= (const float*)d_in[13];
    const float* glob_in_w  = (const float*)d_in[14];
    const float* glob_in_b  = (const float*)d_in[15];
    const float* glob_out_w = (const float*)d_in[16];
    const float* glob_out_b = (const float*)d_in[17];
    const float* cross_in_w = (const float*)d_in[18];
    const float* cross_in_b = (const float*)d_in[19];
    const float* cross_out_w= (const float*)d_in[20];
    const float* cross_out_b= (const float*)d_in[21];
    const float* ln1_g      = (const float*)d_in[22];
    const float* ln1_b      = (const float*)d_in[23];
    const float* w1         = (const float*)d_in[24];
    const float* b1         = (const float*)d_in[25];
    const float* w2         = (const float*)d_in[26];
    const float* b2         = (const float*)d_in[27];
    const float* ln2_g      = (const float*)d_in[28];
    const float* ln2_b      = (const float*)d_in[29];
    const float* pred_w     = (const float*)d_in[30];
    const float* pred_b     = (const float*)d_in[31];
    float* out = (float*)d_out;

    // ---- workspace carve-up (all bf16 except stats) ----
    char* p = (char*)d_ws;
    unsigned short* Wb = (unsigned short*)p; p += 4718592L * 2;        // 9.44 MB
    unsigned short* B[11];
    for (int i = 0; i < 11; ++i) { B[i] = (unsigned short*)p; p += 8388608L; }  // 8 MB each
    unsigned short* Obl    = (unsigned short*)p; p += 1048576L;        // 1024x512
    unsigned short* QKV3L  = (unsigned short*)p; p += 3145728L;        // 1024x1536
    unsigned short* Tb_b   = (unsigned short*)p; p += 8388608L;
    unsigned short* Sglobal_b = (unsigned short*)p; p += 8388608L;
    unsigned short* Fpre_b = (unsigned short*)p; p += 8388608L;
    unsigned short* Tloc_b = (unsigned short*)p; p += 1048576L;        // 1024x512
    float* stats = (float*)p; p += 524288L;

    unsigned short* Mb = B[0];
    unsigned short* Eb = B[1];      unsigned short* Oc_b = B[1];
    unsigned short* QKVb = B[2];    // base QKV (B[2..4]); later cross QKV; later Sb_b
    unsigned short* Sb_b = B[2];
    unsigned short* Ob  = B[5];     // base attn out; later glob attn out
    unsigned short* Sbase_b  = B[6];
    unsigned short* Slocal_b = B[7];
    unsigned short* QKV3 = B[8];    // glob QKV (B[8..10]); later H1
    unsigned short* H1_b = B[8];

    const long oBin = 0, oLin = 786432, oGin = 1572864, oCin = 2359296;
    const long oBout = 3145728, oLout = 3407872, oGout = 3670016, oCout = 3932160;
    const long oW1 = 4194304, oW2 = 4456448;
    const int BIG = 1 << 30;
    const unsigned short* NUS = nullptr;
    const float* NF = nullptr;

    auto GA = [](const unsigned short* A, const unsigned short* A2, int nsplit,
                 const unsigned short* W, const float* bias,
                 unsigned short* Cb, int ldcb, int crem,
                 unsigned short* Cb2, int ldcb2,
                 const unsigned short* r1, const unsigned short* r2,
                 const unsigned short* tl, int relu, int arem) {
        GArgs g; g.A = A; g.A2 = A2; g.nsplit = nsplit; g.W = W; g.bias = bias;
        g.Cb = Cb; g.ldcb = ldcb; g.crem = crem; g.Cb2 = Cb2; g.ldcb2 = ldcb2;
        g.r1 = r1; g.r2 = r2; g.tl = tl; g.relu = relu; g.arem = arem; return g;
    };
    auto FA = [](const unsigned short* Q, const unsigned short* K, const unsigned short* V,
                 unsigned short* O, float* stats, int Nq, int Nkv, int ldq, int ldkv, int causal) {
        FArgs f; f.Q = Q; f.K = K; f.V = V; f.O = O; f.stats = stats;
        f.Nq = Nq; f.Nkv = Nkv; f.ldq = ldq; f.ldkv = ldkv; f.causal = causal; return f;
    };

    // 0. front: weights->bf16, zero Slocal_b, embeddings (one dispatch)
    WP wp; wp.p[0] = base_in_w; wp.p[1] = local_in_w; wp.p[2] = glob_in_w; wp.p[3] = cross_in_w;
    wp.p[4] = base_out_w; wp.p[5] = local_out_w; wp.p[6] = glob_out_w; wp.p[7] = cross_out_w;
    wp.p[8] = w1; wp.p[9] = w2;
    front_kernel<<<10752, 256, 0, stream>>>(wp, Wb, Slocal_b, q, r, qry, M_emb, E_emb, P, Mb, Eb);

    // 1. base MHA: fused QKV, flash, out-proj(+M+E bf16), ln1
    GArgs gBase = GA(Eb, Mb, 512, Wb + oBin, base_in_b, QKVb, 1536, 0, nullptr, 0, NUS, NUS, NUS, 0, 0);
    gemm_bf16<<<dim3(24, 64), 256, 0, stream>>>(gBase, gBase, BIG);
    FArgs fBase = FA(QKVb, QKVb + 512, QKVb + 1024, Ob, stats, 512, 512, 1536, 1536, 1);
    flash_mfma<<<dim3(4, NHEAD, BATCH), 256, 0, stream>>>(fBase, fBase, BIG);
    GArgs gBo = GA(Ob, NUS, BIG, Wb + oBout, base_out_b, Tb_b, 512, 0, nullptr, 0, Mb, Eb, NUS, 0, 0);
    gemm_bf16<<<dim3(8, 64), 256, 0, stream>>>(gBo, gBo, BIG);
    ln_kernel<<<8192, 256, 0, stream>>>(Tb_b, ln1_g, ln1_b, Sbase_b, NF, NF, nullptr);

    // 2. merged glob+local QKV GEMM + attn_w (one dispatch, 2752 blocks)
    GArgs gGin = GA(Sbase_b, NUS, BIG, Wb + oGin, glob_in_b, QKV3, 1536, 0, nullptr, 0, NUS, NUS, NUS, 0, 0);
    GArgs gLin = GA(Sbase_b, NUS, BIG, Wb + oLin, local_in_b, QKV3L, 1536, 0, nullptr, 0, NUS, NUS, NUS, 0, 1);
    gemm_attnw<<<2752, 256, 0, stream>>>(gGin, gLin, 8192, QKVb, QKVb + 512, stats, out + 8192, 1536, 1536);

    // 3. merged glob+local flash
    FArgs fGlob = FA(QKV3, QKV3 + 512, QKV3 + 1024, Ob, nullptr, 512, 512, 1536, 1536, 1);
    FArgs fLoc  = FA(QKV3L, QKV3L + 512, QKV3L + 1024, Obl, nullptr, 64, 64, 1536, 1536, 1);
    flash_mfma<<<dim3(5, NHEAD, BATCH), 256, 0, stream>>>(fGlob, fLoc, 4);

    // 4. merged glob+local out-proj (glob->Sglobal_b; local->Slocal_b scatter + Tloc_b)
    GArgs gGo = GA(Ob, NUS, BIG, Wb + oGout, glob_out_b, Sglobal_b, 512, 0, nullptr, 0, NUS, NUS, NUS, 0, 0);
    GArgs gLo = GA(Obl, NUS, BIG, Wb + oLout, local_out_b, Slocal_b, 512, 1, Tloc_b, 512, NUS, NUS, NUS, 0, 0);
    gemm_bf16<<<dim3(8, 72), 256, 0, stream>>>(gGo, gLo, 8192);

    // 5. cross MHA + fused S-sum epilogue (S = Sc + Sbase + Sglob + Tloc) -> Sb_b
    GArgs gCin = GA(Sbase_b, Slocal_b, 512, Wb + oCin, cross_in_b, QKVb, 1536, 0, nullptr, 0, NUS, NUS, NUS, 0, 0);
    gemm_bf16<<<dim3(24, 64), 256, 0, stream>>>(gCin, gCin, BIG);
    FArgs fCross = FA(QKVb, QKVb + 512, QKVb + 1024, Oc_b, nullptr, 512, 512, 1536, 1536, 0);
    flash_mfma<<<dim3(4, NHEAD, BATCH), 256, 0, stream>>>(fCross, fCross, BIG);
    GArgs gCo = GA(Oc_b, NUS, BIG, Wb + oCout, cross_out_b, Sb_b, 512, 0, nullptr, 0,
                   Sbase_b, Sglobal_b, Tloc_b, 0, 0);
    gemm_bf16<<<dim3(8, 64), 256, 0, stream>>>(gCo, gCo, BIG);

    // 6. FFN (FFN2 adds S residual) + fused LN2+pred
    GArgs gF1 = GA(Sb_b, NUS, BIG, Wb + oW1, b1, H1_b, 512, 0, nullptr, 0, NUS, NUS, NUS, 1, 0);
    gemm_bf16<<<dim3(8, 64), 256, 0, stream>>>(gF1, gF1, BIG);
    GArgs gF2 = GA(H1_b, NUS, BIG, Wb + oW2, b2, Fpre_b, 512, 0, nullptr, 0, Sb_b, NUS, NUS, 0, 0);
    gemm_bf16<<<dim3(8, 64), 256, 0, stream>>>(gF2, gF2, BIG);
    ln_kernel<<<8192, 256, 0, stream>>>(Fpre_b, ln2_g, ln2_b, nullptr, pred_w, pred_b, out);
}

// Round 11
// 495.672 us; speedup vs baseline: 1.3002x; 1.3002x over previous
//
#include <hip/hip_runtime.h>
#include <hip/hip_bf16.h>

#define D_MODEL 512
#define NHEAD 8
#define NSEQ 512
#define BATCH 16
#define LWIN 64
#define S2C 0.18033688f   // 0.125 * log2(e)
#define L2E 1.44269504f

typedef short s16x8 __attribute__((ext_vector_type(8)));
typedef float f32x4 __attribute__((ext_vector_type(4)));

__device__ inline unsigned short f2bf(float f) {
    unsigned int u = __float_as_uint(f);
    u = (u + 0x7fffu + ((u >> 16) & 1u)) >> 16;   // RNE
    return (unsigned short)u;
}
__device__ inline float4 bfl4(const unsigned short* p) {   // 4 bf16 -> float4
    uint2 u = *(const uint2*)p;
    return make_float4(__uint_as_float(u.x << 16), __uint_as_float(u.x & 0xffff0000u),
                       __uint_as_float(u.y << 16), __uint_as_float(u.y & 0xffff0000u));
}
__device__ inline int sw4(int r) { return (r + (r >> 2)) & 3; }

#define GLD16(g, l) __builtin_amdgcn_global_load_lds( \
    (const __attribute__((address_space(1))) void*)(g), \
    (__attribute__((address_space(3))) void*)(l), 16, 0, 0)

struct WP { const float* p[10]; };

// ---------------------------------------------------------------------------
// front: wconv (blocks 0..4607) + zfill Slocal_b (4608..6655) + embed (6656..)
// ---------------------------------------------------------------------------
__global__ __launch_bounds__(256) void front_kernel(
    WP wp, unsigned short* __restrict__ Wb, unsigned short* __restrict__ Z,
    const int* __restrict__ q, const int* __restrict__ r, const int* __restrict__ qry,
    const float* __restrict__ M_emb, const float* __restrict__ E_emb,
    const float* __restrict__ P,
    unsigned short* __restrict__ Mb, unsigned short* __restrict__ Eb)
{
    const int blk = blockIdx.x, tid = threadIdx.x;
    if (blk < 4608) {
        const long e = ((long)blk * 256 + tid) * 4;
        const float* src; long loc;
        if (e < 3145728) { int rg = (int)(e / 786432); src = wp.p[rg]; loc = e - (long)rg * 786432; }
        else { long j = e - 3145728; int rg = (int)(j >> 18); src = wp.p[4 + rg]; loc = j - ((long)rg << 18); }
        float4 v = *(const float4*)(src + loc);
        ushort4 o; o.x = f2bf(v.x); o.y = f2bf(v.y); o.z = f2bf(v.z); o.w = f2bf(v.w);
        *(ushort4*)(Wb + e) = o;
    } else if (blk < 6656) {
        const long i = ((long)(blk - 4608) * 256 + tid) * 8;
        *(uint4*)(Z + i) = make_uint4(0u, 0u, 0u, 0u);
    } else {
        const int t = (blk - 6656) * 2 + (tid >> 7);    // row b*N+n
        const int i = tid & 127;
        const int n = t & (NSEQ - 1);
        const int x = q[t] + 10000 * r[t];
        const int e = qry[t];
        float4 a = ((const float4*)(M_emb + (long)x * D_MODEL))[i];
        float4 p4 = ((const float4*)(P + (long)n * D_MODEL))[i];
        float4 ev = ((const float4*)(E_emb + (long)e * D_MODEL))[i];
        float4 mv = make_float4(a.x + p4.x, a.y + p4.y, a.z + p4.z, a.w + p4.w);
        ushort4 mb; mb.x = f2bf(mv.x); mb.y = f2bf(mv.y); mb.z = f2bf(mv.z); mb.w = f2bf(mv.w);
        ushort4 eb; eb.x = f2bf(ev.x); eb.y = f2bf(ev.y); eb.z = f2bf(ev.z); eb.w = f2bf(ev.w);
        *(ushort4*)(Mb + (long)t * D_MODEL + i * 4) = mb;
        *(ushort4*)(Eb + (long)t * D_MODEL + i * 4) = eb;
    }
}

// ---------------------------------------------------------------------------
// bf16 MFMA GEMM, 128M x 64N tile, GLD16 staging (round-8 core).
// All residuals and outputs bf16; fp32 accumulate in-register/epilogue.
// Dual arg-set: blocks with m0 >= msplit use g1 (with m0 -= msplit).
// ---------------------------------------------------------------------------
struct GArgs {
    const unsigned short* A; const unsigned short* A2; int nsplit;
    const unsigned short* W; const float* bias;
    unsigned short* Cb; int ldcb; int crem;
    unsigned short* Cb2; int ldcb2;
    const unsigned short* r1; const unsigned short* r2; const unsigned short* tl;
    int relu; int arem;
};

__global__ __launch_bounds__(256) void gemm_bf16(GArgs g0, GArgs g1, int msplit)
{
    __shared__ __align__(16) unsigned short Sh[6144];   // A 128x32 | W 64x32 ; epi: 32x68 f32
    unsigned short* As = Sh;
    unsigned short* Ws = Sh + 4096;
    float* Shf = (float*)Sh;

    int m0 = blockIdx.y * 128;
    const GArgs& G = (m0 < msplit) ? g0 : g1;
    if (m0 >= msplit) m0 -= msplit;

    const int tid = threadIdx.x, lane = tid & 63, wid = tid >> 6;
    const int n0 = blockIdx.x * 64;
    const int lm = lane & 15;
    const int lq = lane >> 4;
    const unsigned short* Asel = (n0 >= G.nsplit) ? G.A2 : G.A;

    const int rlane = lane >> 2, clane = lane & 3;
    const int lr0 = wid * 16 + rlane;          // 0..63
    const int lr1 = 64 + lr0;                  // 64..127 (A only)
    int rgA0 = m0 + lr0, rgA1 = m0 + lr1;
    if (G.arem) {
        rgA0 = ((rgA0 >> 6) << 9) + (NSEQ - LWIN) + (rgA0 & 63);
        rgA1 = ((rgA1 >> 6) << 9) + (NSEQ - LWIN) + (rgA1 & 63);
    }
    const unsigned short* pA0 = Asel + (long)rgA0 * 512 + ((clane ^ sw4(lr0)) << 3);
    const unsigned short* pA1 = Asel + (long)rgA1 * 512 + ((clane ^ sw4(lr1)) << 3);
    const unsigned short* pW0 = G.W + (long)(n0 + lr0) * 512 + ((clane ^ sw4(lr0)) << 3);
    unsigned short* lA0 = As + (wid * 16) * 32;
    unsigned short* lA1 = As + (64 + wid * 16) * 32;
    unsigned short* lW0 = Ws + (wid * 16) * 32;

    f32x4 acc[2][4];
    #pragma unroll
    for (int i = 0; i < 2; ++i)
        #pragma unroll
        for (int j = 0; j < 4; ++j) acc[i][j] = (f32x4){0.f, 0.f, 0.f, 0.f};

    for (int k0 = 0; k0 < 512; k0 += 32) {
        __syncthreads();
        GLD16(pA0 + k0, lA0);
        GLD16(pA1 + k0, lA1);
        GLD16(pW0 + k0, lW0);
        __syncthreads();

        s16x8 af[2], wf[4];
        #pragma unroll
        for (int i = 0; i < 2; ++i) {
            const int ra = wid * 32 + i * 16 + lm;
            af[i] = *(const s16x8*)&As[ra * 32 + ((lq ^ sw4(ra)) << 3)];
        }
        #pragma unroll
        for (int j = 0; j < 4; ++j) {
            const int rw = j * 16 + lm;
            wf[j] = *(const s16x8*)&Ws[rw * 32 + ((lq ^ sw4(rw)) << 3)];
        }
        #pragma unroll
        for (int i = 0; i < 2; ++i)
            #pragma unroll
            for (int j = 0; j < 4; ++j)
                acc[i][j] = __builtin_amdgcn_mfma_f32_16x16x32_bf16(af[i], wf[j], acc[i][j], 0, 0, 0);
    }

    const int fr = lane & 15;
    const int q4 = (lane >> 4) * 4;
    for (int qtr = 0; qtr < 4; ++qtr) {
        __syncthreads();
        if (wid == qtr) {
            #pragma unroll
            for (int j = 0; j < 4; ++j) {
                const int lcol = j * 16 + fr;
                const float bv = G.bias[n0 + lcol];
                #pragma unroll
                for (int i = 0; i < 2; ++i) {
                    #pragma unroll
                    for (int rg = 0; rg < 4; ++rg) {
                        float v = acc[i][j][rg] + bv;
                        if (G.relu) v = fmaxf(v, 0.f);
                        Shf[(i * 16 + q4 + rg) * 68 + lcol] = v;
                    }
                }
            }
        }
        __syncthreads();
        #pragma unroll
        for (int it = 0; it < 2; ++it) {
            const int flat = it * 256 + tid;
            const int rowq = flat >> 4, k4 = flat & 15;
            const int grow = m0 + qtr * 32 + rowq;
            const int gcol = n0 + k4 * 4;
            float4 f = *(const float4*)&Shf[rowq * 68 + k4 * 4];
            if (G.r1) {
                float4 a = bfl4(G.r1 + (long)grow * 512 + gcol);
                f.x += a.x; f.y += a.y; f.z += a.z; f.w += a.w;
            }
            if (G.r2) {
                float4 b = bfl4(G.r2 + (long)grow * 512 + gcol);
                f.x += b.x; f.y += b.y; f.z += b.z; f.w += b.w;
            }
            if (G.tl) {
                const int n = grow & 511;
                if (n >= NSEQ - LWIN) {
                    float4 c = bfl4(G.tl + ((long)(grow >> 9) * 64 + (n - (NSEQ - LWIN))) * 512 + gcol);
                    f.x += c.x; f.y += c.y; f.z += c.z; f.w += c.w;
                }
            }
            ushort4 u; u.x = f2bf(f.x); u.y = f2bf(f.y); u.z = f2bf(f.z); u.w = f2bf(f.w);
            if (G.Cb) {
                const int crow = G.crem ? (((grow >> 6) << 9) + (NSEQ - LWIN) + (grow & 63)) : grow;
                *(ushort4*)(G.Cb + (long)crow * G.ldcb + gcol) = u;
            }
            if (G.Cb2) *(ushort4*)(G.Cb2 + (long)grow * G.ldcb2 + gcol) = u;
        }
    }
}

// ---------------------------------------------------------------------------
// attn_w (transposed MFMA): head-mean base probs via saved (m,l). grid (8,8,B).
// ---------------------------------------------------------------------------
__global__ __launch_bounds__(256) void attn_w_kernel(
    const unsigned short* __restrict__ Q, const unsigned short* __restrict__ K,
    const float* __restrict__ stats, float* __restrict__ AW, int ldq, int ldk)
{
    const int kt = blockIdx.x, qt = blockIdx.y, b = blockIdx.z;
    const int tid = threadIdx.x;
    if (kt > qt) {
        const int tx = tid & 15, ty = tid >> 4;
        #pragma unroll
        for (int i = 0; i < 4; ++i)
            *(float4*)(AW + ((long)b * NSEQ + qt * 64 + ty * 4 + i) * NSEQ + kt * 64 + tx * 4)
                = make_float4(0.f, 0.f, 0.f, 0.f);
        return;
    }
    __shared__ __align__(16) unsigned short Ks[64 * 72];
    const int lane = tid & 63, w = tid >> 6;
    const int lm = lane & 15, lq = lane >> 4;
    const int skey = tid >> 3, sd = (tid & 7) * 8;
    const long qrow = (long)b * NSEQ + qt * 64 + w * 16 + lm;

    f32x4 aw[4];
    #pragma unroll
    for (int t = 0; t < 4; ++t) aw[t] = (f32x4){0.f,0.f,0.f,0.f};

    for (int h = 0; h < NHEAD; ++h) {
        __syncthreads();
        {
            const long kb = ((long)b * NSEQ + kt * 64) * ldk + h * 64;
            *(s16x8*)&Ks[skey * 72 + sd] = *(const s16x8*)(K + kb + (long)skey * ldk + sd);
            *(s16x8*)&Ks[(skey + 32) * 72 + sd] = *(const s16x8*)(K + kb + (long)(skey + 32) * ldk + sd);
        }
        __syncthreads();
        s16x8 a0, a1;
        {
            const unsigned short* qp = Q + qrow * ldq + h * 64 + lq * 8;
            a0 = *(const s16x8*)qp; a1 = *(const s16x8*)(qp + 32);
        }
        f32x4 sc[4];
        #pragma unroll
        for (int t = 0; t < 4; ++t) sc[t] = (f32x4){0.f,0.f,0.f,0.f};
        #pragma unroll
        for (int t = 0; t < 4; ++t) {
            s16x8 k0 = *(const s16x8*)&Ks[(t * 16 + lm) * 72 + lq * 8];
            s16x8 k1 = *(const s16x8*)&Ks[(t * 16 + lm) * 72 + lq * 8 + 32];
            sc[t] = __builtin_amdgcn_mfma_f32_16x16x32_bf16(k0, a0, sc[t], 0, 0, 0);
            sc[t] = __builtin_amdgcn_mfma_f32_16x16x32_bf16(k1, a1, sc[t], 0, 0, 0);
        }
        float2 ml = *(const float2*)(stats + (((long)b * NHEAD + h) * NSEQ + qt * 64 + w * 16 + lm) * 2);
        const float mb2 = ml.x * L2E;
        const float sca = 0.125f / ml.y;
        #pragma unroll
        for (int t = 0; t < 4; ++t)
            #pragma unroll
            for (int r = 0; r < 4; ++r) {
                const bool masked = (kt == qt) && (t * 16 + lq * 4 + r > w * 16 + lm);
                if (!masked) aw[t][r] += exp2f(sc[t][r] * S2C - mb2) * sca;
            }
    }
    #pragma unroll
    for (int t = 0; t < 4; ++t)
        *(float4*)(AW + qrow * NSEQ + kt * 64 + t * 16 + lq * 4) = float4{aw[t][0], aw[t][1], aw[t][2], aw[t][3]};
}

// ---------------------------------------------------------------------------
// Transposed MFMA flash attention, paired q-tiles (round-8 core, dual args).
// ---------------------------------------------------------------------------
struct FArgs {
    const unsigned short* Q; const unsigned short* K; const unsigned short* V;
    unsigned short* O; float* stats; int Nq, Nkv, ldq, ldkv, causal;
};

__global__ __launch_bounds__(256) void flash_mfma(FArgs f0, FArgs f1, int xsplit)
{
    __shared__ __align__(16) unsigned short Ks[64 * 72];   // [key][dim]
    __shared__ __align__(16) unsigned short Pl[64 * 72];   // [q][key] bf16
    __shared__ __align__(16) unsigned int   Vt[64 * 36];   // [dim][keypair] swizzled

    const FArgs& F = ((int)blockIdx.x < xsplit) ? f0 : f1;
    const int bx = ((int)blockIdx.x < xsplit) ? blockIdx.x : (blockIdx.x - xsplit);

    const int tid = threadIdx.x, lane = tid & 63, w = tid >> 6;
    const int lm = lane & 15, lq = lane >> 4;
    const int h = blockIdx.y, b = blockIdx.z;
    const int Nq = F.Nq, Nkv = F.Nkv, ldq = F.ldq, ldkv = F.ldkv, causal = F.causal;
    const int nqt = Nq >> 6;
    const int qa = bx, qb = nqt - 1 - qa;
    const bool single = (qa == qb);

    s16x8 aqA0, aqA1, aqB0, aqB1;
    {
        const unsigned short* qp = F.Q + ((long)b * Nq + qb * 64 + w * 16 + lm) * ldq + h * 64 + lq * 8;
        aqB0 = *(const s16x8*)qp; aqB1 = *(const s16x8*)(qp + 32);
    }
    if (!single) {
        const unsigned short* qp = F.Q + ((long)b * Nq + qa * 64 + w * 16 + lm) * ldq + h * 64 + lq * 8;
        aqA0 = *(const s16x8*)qp; aqA1 = *(const s16x8*)(qp + 32);
    }

    float mA = -INFINITY, lA = 0.f, mB = -INFINITY, lB = 0.f;
    f32x4 oA[4], oB[4];
    #pragma unroll
    for (int t = 0; t < 4; ++t) { oA[t] = (f32x4){0.f,0.f,0.f,0.f}; oB[t] = (f32x4){0.f,0.f,0.f,0.f}; }

    const int nkt = causal ? (qb + 1) : (Nkv >> 6);
    const int skey = tid >> 3, sd = (tid & 7) * 8;

    s16x8 kr0, kr1; uint4 vr0, vr1;
    {
        const long kb = ((long)b * Nkv) * ldkv + h * 64;
        kr0 = *(const s16x8*)(F.K + kb + (long)skey * ldkv + sd);
        kr1 = *(const s16x8*)(F.K + kb + (long)(skey + 32) * ldkv + sd);
        const unsigned short* vp = F.V + ((long)b * Nkv + 2 * skey) * ldkv + h * 64 + sd;
        vr0 = *(const uint4*)vp; vr1 = *(const uint4*)(vp + ldkv);
    }

    auto process = [&](s16x8 a0, s16x8 a1, float& m, float& l, f32x4* oacc, bool diag) {
        f32x4 sc[4];
        #pragma unroll
        for (int t = 0; t < 4; ++t) sc[t] = (f32x4){0.f,0.f,0.f,0.f};
        #pragma unroll
        for (int t = 0; t < 4; ++t) {
            s16x8 k0 = *(const s16x8*)&Ks[(t * 16 + lm) * 72 + lq * 8];
            s16x8 k1 = *(const s16x8*)&Ks[(t * 16 + lm) * 72 + lq * 8 + 32];
            sc[t] = __builtin_amdgcn_mfma_f32_16x16x32_bf16(k0, a0, sc[t], 0, 0, 0);
            sc[t] = __builtin_amdgcn_mfma_f32_16x16x32_bf16(k1, a1, sc[t], 0, 0, 0);
        }
        if (diag) {
            #pragma unroll
            for (int t = 0; t < 4; ++t)
                #pragma unroll
                for (int r = 0; r < 4; ++r)
                    if (t * 16 + lq * 4 + r > w * 16 + lm) sc[t][r] = -INFINITY;
        }
        float mt = sc[0][0];
        #pragma unroll
        for (int t = 0; t < 4; ++t)
            #pragma unroll
            for (int r = 0; r < 4; ++r) mt = fmaxf(mt, sc[t][r]);
        mt = fmaxf(mt, __shfl_xor(mt, 16));
        mt = fmaxf(mt, __shfl_xor(mt, 32));
        const float mn = fmaxf(m, mt);
        const float al = exp2f((m - mn) * S2C);
        float rs = 0.f;
        #pragma unroll
        for (int t = 0; t < 4; ++t)
            #pragma unroll
            for (int r = 0; r < 4; ++r) {
                float p = exp2f((sc[t][r] - mn) * S2C);
                sc[t][r] = p; rs += p;
            }
        rs += __shfl_xor(rs, 16);
        rs += __shfl_xor(rs, 32);
        m = mn; l = l * al + rs;
        #pragma unroll
        for (int t = 0; t < 4; ++t) oacc[t] *= al;
        #pragma unroll
        for (int t = 0; t < 4; ++t) {
            ushort4 u;
            u.x = f2bf(sc[t][0]); u.y = f2bf(sc[t][1]);
            u.z = f2bf(sc[t][2]); u.w = f2bf(sc[t][3]);
            *(ushort4*)&Pl[(w * 16 + lm) * 72 + t * 16 + lq * 4] = u;
        }
        #pragma unroll
        for (int ks = 0; ks < 2; ++ks) {
            s16x8 bp = *(const s16x8*)&Pl[(w * 16 + lm) * 72 + ks * 32 + lq * 8];
            #pragma unroll
            for (int t = 0; t < 4; ++t) {
                const int row = t * 16 + lm;
                const int pg = ((lq >> 1) + 2 * ks) ^ ((row >> 3) & 3);
                s16x8 av = *(const s16x8*)((const unsigned short*)Vt + row * 72 + pg * 16 + (lq & 1) * 8);
                oacc[t] = __builtin_amdgcn_mfma_f32_16x16x32_bf16(av, bp, oacc[t], 0, 0, 0);
            }
        }
    };

    for (int kt = 0; kt < nkt; ++kt) {
        __syncthreads();
        *(s16x8*)&Ks[skey * 72 + sd] = kr0;
        *(s16x8*)&Ks[(skey + 32) * 72 + sd] = kr1;
        {
            unsigned pw[8];
            pw[0] = (vr0.x & 0xffffu) | (vr1.x << 16);
            pw[1] = (vr0.x >> 16)     | (vr1.x & 0xffff0000u);
            pw[2] = (vr0.y & 0xffffu) | (vr1.y << 16);
            pw[3] = (vr0.y >> 16)     | (vr1.y & 0xffff0000u);
            pw[4] = (vr0.z & 0xffffu) | (vr1.z << 16);
            pw[5] = (vr0.z >> 16)     | (vr1.z & 0xffff0000u);
            pw[6] = (vr0.w & 0xffffu) | (vr1.w << 16);
            pw[7] = (vr0.w >> 16)     | (vr1.w & 0xffff0000u);
            #pragma unroll
            for (int j = 0; j < 8; ++j) {
                const int row = sd + j;
                const int col = (((skey >> 3) ^ ((row >> 3) & 3)) << 3) | (skey & 7);
                Vt[row * 36 + col] = pw[j];
            }
        }
        __syncthreads();
        if (kt + 1 < nkt) {
            const long kb = ((long)b * Nkv + (kt + 1) * 64) * ldkv + h * 64;
            kr0 = *(const s16x8*)(F.K + kb + (long)skey * ldkv + sd);
            kr1 = *(const s16x8*)(F.K + kb + (long)(skey + 32) * ldkv + sd);
            const unsigned short* vp = F.V + ((long)b * Nkv + (kt + 1) * 64 + 2 * skey) * ldkv + h * 64 + sd;
            vr0 = *(const uint4*)vp; vr1 = *(const uint4*)(vp + ldkv);
        }
        process(aqB0, aqB1, mB, lB, oB, causal && (kt == qb));
        if (!single && (!causal || kt <= qa))
            process(aqA0, aqA1, mA, lA, oA, causal && (kt == qa));
    }

    {
        const float inv = 1.0f / lB;
        const long orow = ((long)b * Nq + qb * 64 + w * 16 + lm) * D_MODEL + h * 64;
        #pragma unroll
        for (int t = 0; t < 4; ++t) {
            ushort4 u;
            u.x = f2bf(oB[t][0] * inv); u.y = f2bf(oB[t][1] * inv);
            u.z = f2bf(oB[t][2] * inv); u.w = f2bf(oB[t][3] * inv);
            *(ushort4*)(F.O + orow + t * 16 + lq * 4) = u;
        }
    }
    if (!single) {
        const float inv = 1.0f / lA;
        const long orow = ((long)b * Nq + qa * 64 + w * 16 + lm) * D_MODEL + h * 64;
        #pragma unroll
        for (int t = 0; t < 4; ++t) {
            ushort4 u;
            u.x = f2bf(oA[t][0] * inv); u.y = f2bf(oA[t][1] * inv);
            u.z = f2bf(oA[t][2] * inv); u.w = f2bf(oA[t][3] * inv);
            *(ushort4*)(F.O + orow + t * 16 + lq * 4) = u;
        }
    }
    if (F.stats && lq == 0) {
        long idx = (((long)b * NHEAD + h) * Nq + qb * 64 + w * 16 + lm) * 2;
        F.stats[idx] = mB * 0.125f; F.stats[idx + 1] = lB;
        if (!single) {
            idx = (((long)b * NHEAD + h) * Nq + qa * 64 + w * 16 + lm) * 2;
            F.stats[idx] = mA * 0.125f; F.stats[idx + 1] = lA;
        }
    }
}

// ---------------------------------------------------------------------------
// LayerNorm, bf16 input (residuals pre-added upstream); optional fused pred.
// ---------------------------------------------------------------------------
__global__ __launch_bounds__(256) void ln_kernel(
    const unsigned short* __restrict__ X, const float* __restrict__ g,
    const float* __restrict__ bb, unsigned short* __restrict__ outb,
    const float* __restrict__ pw, const float* __restrict__ pb,
    float* __restrict__ outp)
{
    const long row = blockIdx.x;
    const int tid = threadIdx.x;
    __shared__ float red[256];
    const long base = row * D_MODEL;
    const unsigned ux = *(const unsigned*)(X + base + tid * 2);
    const float v0 = __uint_as_float(ux << 16);
    const float v1 = __uint_as_float(ux & 0xffff0000u);
    red[tid] = v0 + v1; __syncthreads();
    for (int s = 128; s > 0; s >>= 1) {
        if (tid < s) red[tid] += red[tid + s];
        __syncthreads();
    }
    const float mean = red[0] * (1.f / 512.f);
    __syncthreads();
    const float d0 = v0 - mean, d1 = v1 - mean;
    red[tid] = d0 * d0 + d1 * d1; __syncthreads();
    for (int s = 128; s > 0; s >>= 1) {
        if (tid < s) red[tid] += red[tid + s];
        __syncthreads();
    }
    const float rstd = rsqrtf(red[0] * (1.f / 512.f) + 1e-5f);
    const float2 gv = *(const float2*)(g + tid * 2);
    const float2 bv = *(const float2*)(bb + tid * 2);
    const float y0 = d0 * rstd * gv.x + bv.x;
    const float y1 = d1 * rstd * gv.y + bv.y;
    if (pw) {
        const float2 pv = *(const float2*)(pw + tid * 2);
        float s = y0 * pv.x + y1 * pv.y;
        __syncthreads();
        red[tid] = s; __syncthreads();
        for (int st = 128; st > 0; st >>= 1) {
            if (tid < st) red[tid] += red[tid + st];
            __syncthreads();
        }
        if (tid == 0) outp[row] = 1.f / (1.f + __expf(-(red[0] + pb[0])));
        return;
    }
    const unsigned o = (unsigned)f2bf(y0) | ((unsigned)f2bf(y1) << 16);
    *(unsigned*)(outb + base + tid * 2) = o;
}

// ---------------------------------------------------------------------------
extern "C" void kernel_launch(void* const* d_in, const int* in_sizes, int n_in,
                              void* d_out, int out_size, void* d_ws, size_t ws_size,
                              hipStream_t stream)
{
    const int*   q          = (const int*)d_in[0];
    const int*   r          = (const int*)d_in[1];
    const int*   qry        = (const int*)d_in[2];
    const float* M_emb      = (const float*)d_in[3];
    const float* E_emb      = (const float*)d_in[4];
    const float* P          = (const float*)d_in[5];
    const float* base_in_w  = (const float*)d_in[6];
    const float* base_in_b  = (const float*)d_in[7];
    const float* base_out_w = (const float*)d_in[8];
    const float* base_out_b = (const float*)d_in[9];
    const float* local_in_w = (const float*)d_in[10];
    const float* local_in_b = (const float*)d_in[11];
    const float* local_out_w= (const float*)d_in[12];
    const float* local_out_b= (const float*)d_in[13];
    const float* glob_in_w  = (const float*)d_in[14];
    const float* glob_in_b  = (const float*)d_in[15];
    const float* glob_out_w = (const float*)d_in[16];
    const float* glob_out_b = (const float*)d_in[17];
    const float* cross_in_w = (const float*)d_in[18];
    const float* cross_in_b = (const float*)d_in[19];
    const float* cross_out_w= (const float*)d_in[20];
    const float* cross_out_b= (const float*)d_in[21];
    const float* ln1_g      = (const float*)d_in[22];
    const float* ln1_b      = (const float*)d_in[23];
    const float* w1         = (const float*)d_in[24];
    const float* b1         = (const float*)d_in[25];
    const float* w2         = (const float*)d_in[26];
    const float* b2         = (const float*)d_in[27];
    const float* ln2_g      = (const float*)d_in[28];
    const float* ln2_b      = (const float*)d_in[29];
    const float* pred_w     = (const float*)d_in[30];
    const float* pred_b     = (const float*)d_in[31];
    float* out = (float*)d_out;

    // ---- workspace carve-up (all bf16 except stats) ----
    char* p = (char*)d_ws;
    unsigned short* Wb = (unsigned short*)p; p += 4718592L * 2;        // 9.44 MB
    unsigned short* B[11];
    for (int i = 0; i < 11; ++i) { B[i] = (unsigned short*)p; p += 8388608L; }  // 8 MB each
    unsigned short* Obl    = (unsigned short*)p; p += 1048576L;        // 1024x512
    unsigned short* QKV3L  = (unsigned short*)p; p += 3145728L;        // 1024x1536
    unsigned short* Tb_b   = (unsigned short*)p; p += 8388608L;
    unsigned short* Sglobal_b = (unsigned short*)p; p += 8388608L;
    unsigned short* Fpre_b = (unsigned short*)p; p += 8388608L;
    unsigned short* Tloc_b = (unsigned short*)p; p += 1048576L;        // 1024x512
    float* stats = (float*)p; p += 524288L;

    unsigned short* Mb = B[0];
    unsigned short* Eb = B[1];      unsigned short* Oc_b = B[1];
    unsigned short* QKVb = B[2];    // base QKV (B[2..4]); later cross QKV; later Sb_b
    unsigned short* Sb_b = B[2];
    unsigned short* Ob  = B[5];     // base attn out; later glob attn out
    unsigned short* Sbase_b  = B[6];
    unsigned short* Slocal_b = B[7];
    unsigned short* QKV3 = B[8];    // glob QKV (B[8..10]); later H1
    unsigned short* H1_b = B[8];

    const long oBin = 0, oLin = 786432, oGin = 1572864, oCin = 2359296;
    const long oBout = 3145728, oLout = 3407872, oGout = 3670016, oCout = 3932160;
    const long oW1 = 4194304, oW2 = 4456448;
    const int BIG = 1 << 30;
    const unsigned short* NUS = nullptr;
    const float* NF = nullptr;

    auto GA = [](const unsigned short* A, const unsigned short* A2, int nsplit,
                 const unsigned short* W, const float* bias,
                 unsigned short* Cb, int ldcb, int crem,
                 unsigned short* Cb2, int ldcb2,
                 const unsigned short* r1, const unsigned short* r2,
                 const unsigned short* tl, int relu, int arem) {
        GArgs g; g.A = A; g.A2 = A2; g.nsplit = nsplit; g.W = W; g.bias = bias;
        g.Cb = Cb; g.ldcb = ldcb; g.crem = crem; g.Cb2 = Cb2; g.ldcb2 = ldcb2;
        g.r1 = r1; g.r2 = r2; g.tl = tl; g.relu = relu; g.arem = arem; return g;
    };
    auto FA = [](const unsigned short* Q, const unsigned short* K, const unsigned short* V,
                 unsigned short* O, float* stats, int Nq, int Nkv, int ldq, int ldkv, int causal) {
        FArgs f; f.Q = Q; f.K = K; f.V = V; f.O = O; f.stats = stats;
        f.Nq = Nq; f.Nkv = Nkv; f.ldq = ldq; f.ldkv = ldkv; f.causal = causal; return f;
    };

    // 0. front: weights->bf16, zero Slocal_b, embeddings (one dispatch)
    WP wp; wp.p[0] = base_in_w; wp.p[1] = local_in_w; wp.p[2] = glob_in_w; wp.p[3] = cross_in_w;
    wp.p[4] = base_out_w; wp.p[5] = local_out_w; wp.p[6] = glob_out_w; wp.p[7] = cross_out_w;
    wp.p[8] = w1; wp.p[9] = w2;
    front_kernel<<<10752, 256, 0, stream>>>(wp, Wb, Slocal_b, q, r, qry, M_emb, E_emb, P, Mb, Eb);

    // 1. base MHA: fused QKV, flash, attn_w, out-proj(+M+E bf16), ln1
    GArgs gBase = GA(Eb, Mb, 512, Wb + oBin, base_in_b, QKVb, 1536, 0, nullptr, 0, NUS, NUS, NUS, 0, 0);
    gemm_bf16<<<dim3(24, 64), 256, 0, stream>>>(gBase, gBase, BIG);
    FArgs fBase = FA(QKVb, QKVb + 512, QKVb + 1024, Ob, stats, 512, 512, 1536, 1536, 1);
    flash_mfma<<<dim3(4, NHEAD, BATCH), 256, 0, stream>>>(fBase, fBase, BIG);
    attn_w_kernel<<<dim3(8, 8, BATCH), 256, 0, stream>>>(QKVb, QKVb + 512, stats, out + 8192, 1536, 1536);
    GArgs gBo = GA(Ob, NUS, BIG, Wb + oBout, base_out_b, Tb_b, 512, 0, nullptr, 0, Mb, Eb, NUS, 0, 0);
    gemm_bf16<<<dim3(8, 64), 256, 0, stream>>>(gBo, gBo, BIG);
    ln_kernel<<<8192, 256, 0, stream>>>(Tb_b, ln1_g, ln1_b, Sbase_b, NF, NF, nullptr);

    // 2. merged glob+local QKV GEMM (dual arg-set, 24x72 grid)
    GArgs gGin = GA(Sbase_b, NUS, BIG, Wb + oGin, glob_in_b, QKV3, 1536, 0, nullptr, 0, NUS, NUS, NUS, 0, 0);
    GArgs gLin = GA(Sbase_b, NUS, BIG, Wb + oLin, local_in_b, QKV3L, 1536, 0, nullptr, 0, NUS, NUS, NUS, 0, 1);
    gemm_bf16<<<dim3(24, 72), 256, 0, stream>>>(gGin, gLin, 8192);

    // 3. merged glob+local flash
    FArgs fGlob = FA(QKV3, QKV3 + 512, QKV3 + 1024, Ob, nullptr, 512, 512, 1536, 1536, 1);
    FArgs fLoc  = FA(QKV3L, QKV3L + 512, QKV3L + 1024, Obl, nullptr, 64, 64, 1536, 1536, 1);
    flash_mfma<<<dim3(5, NHEAD, BATCH), 256, 0, stream>>>(fGlob, fLoc, 4);

    // 4. merged glob+local out-proj (glob->Sglobal_b; local->Slocal_b scatter + Tloc_b)
    GArgs gGo = GA(Ob, NUS, BIG, Wb + oGout, glob_out_b, Sglobal_b, 512, 0, nullptr, 0, NUS, NUS, NUS, 0, 0);
    GArgs gLo = GA(Obl, NUS, BIG, Wb + oLout, local_out_b, Slocal_b, 512, 1, Tloc_b, 512, NUS, NUS, NUS, 0, 0);
    gemm_bf16<<<dim3(8, 72), 256, 0, stream>>>(gGo, gLo, 8192);

    // 5. cross MHA + fused S-sum epilogue (S = Sc + Sbase + Sglob + Tloc) -> Sb_b
    GArgs gCin = GA(Sbase_b, Slocal_b, 512, Wb + oCin, cross_in_b, QKVb, 1536, 0, nullptr, 0, NUS, NUS, NUS, 0, 0);
    gemm_bf16<<<dim3(24, 64), 256, 0, stream>>>(gCin, gCin, BIG);
    FArgs fCross = FA(QKVb, QKVb + 512, QKVb + 1024, Oc_b, nullptr, 512, 512, 1536, 1536, 0);
    flash_mfma<<<dim3(4, NHEAD, BATCH), 256, 0, stream>>>(fCross, fCross, BIG);
    GArgs gCo = GA(Oc_b, NUS, BIG, Wb + oCout, cross_out_b, Sb_b, 512, 0, nullptr, 0,
                   Sbase_b, Sglobal_b, Tloc_b, 0, 0);
    gemm_bf16<<<dim3(8, 64), 256, 0, stream>>>(gCo, gCo, BIG);

    // 6. FFN (FFN2 adds S residual) + fused LN2+pred
    GArgs gF1 = GA(Sb_b, NUS, BIG, Wb + oW1, b1, H1_b, 512, 0, nullptr, 0, NUS, NUS, NUS, 1, 0);
    gemm_bf16<<<dim3(8, 64), 256, 0, stream>>>(gF1, gF1, BIG);
    GArgs gF2 = GA(H1_b, NUS, BIG, Wb + oW2, b2, Fpre_b, 512, 0, nullptr, 0, Sb_b, NUS, NUS, 0, 0);
    gemm_bf16<<<dim3(8, 64), 256, 0, stream>>>(gF2, gF2, BIG);
    ln_kernel<<<8192, 256, 0, stream>>>(Fpre_b, ln2_g, ln2_b, nullptr, pred_w, pred_b, out);
}